// Round 10
// baseline (3844.368 us; speedup 1.0000x reference)
//
#include <hip/hip_runtime.h>

#define NB 128      // batch
#define NH 1024     // hidden
#define NS 256      // conditioning sequence length
#define NF 8        // forecast length
#define NBLK 192    // persistent blocks: 64 L0 (16 cols) | 128 L1 (8 cols, gi+gh fused)
#define NTH 512     // 8 waves
#define AG  __HIP_MEMORY_SCOPE_AGENT

// barrier line indices (uint32 units; distinct >=128B-separated lines)
#define GLOBL 0            // MALL line: ONLY 8 rank0s add; nobody polls (last-detect)
#define RELL  64           // MALL line: 1 adder, 192 atomic-load pollers (R5-proven)
#define INITL 128
#define XCNT  192          // +32*xcd  (init registration)
#define XARR  512          // +32*xcd  (XCD-local L2: arrival, atomic RMW poll)
#define XCPY  1024         // +32*xcd  (XCD-local L2: copy barrier, atomic RMW poll)

typedef _Float16 half_t;
typedef _Float16 f16x8 __attribute__((ext_vector_type(8)));
typedef float f32x4 __attribute__((ext_vector_type(4)));
typedef unsigned long long u64;

struct GP {
    const float *x, *hin, *Wih0, *Whh0, *bih0, *bhh0, *Wih1, *Whh1, *bih1, *bhh1, *fcw, *fcb;
    float *ypart, *out;
    half_t *h0b0, *h0b1, *h1b0, *h1b1;
    char *reg;            // XCD-private A regions: [8 xcd][2 slot][h0 256K | h1 256K]
    unsigned *bar;
};

__device__ __forceinline__ float fast_sigmoid(float x) { return 1.0f / (1.0f + __expf(-x)); }
__device__ __forceinline__ float fast_tanh(float x) {
    float e = __expf(2.0f * x);
    return (e - 1.0f) / (e + 1.0f);
}

// ---- agent-scope (sc1 / MALL) accesses ----
__device__ __forceinline__ u64 ldu64(const void* p) {
    return __hip_atomic_load((const u64*)p, __ATOMIC_RELAXED, AG);
}
__device__ __forceinline__ void stu64(void* p, u64 v) {
    __hip_atomic_store((u64*)p, v, __ATOMIC_RELAXED, AG);
}
__device__ __forceinline__ float ldf32(const float* p) {
    return __hip_atomic_load(p, __ATOMIC_RELAXED, AG);
}
__device__ __forceinline__ void stf32(float* p, float v) {
    __hip_atomic_store(p, v, __ATOMIC_RELAXED, AG);
}
__device__ __forceinline__ unsigned aadd(unsigned* p, unsigned v) {
    return __hip_atomic_fetch_add(p, v, __ATOMIC_RELAXED, AG);
}
__device__ __forceinline__ unsigned ald(const unsigned* p) {   // sc1 atomic load (MALL-fresh)
    return __hip_atomic_load(p, __ATOMIC_RELAXED, AG);
}

// ---- XCD-local atomics (no sc1 -> execute in the local XCD's L2; always fresh) ----
__device__ __forceinline__ void l2add(unsigned* p, unsigned v) {
    asm volatile("global_atomic_add %0, %1, off" :: "v"(p), "v"(v) : "memory");
}
__device__ __forceinline__ unsigned l2add_rtn(unsigned* p, unsigned v) {
    unsigned ret;
    asm volatile("global_atomic_add %0, %1, %2, off sc0\n\ts_waitcnt vmcnt(0)"
                 : "=v"(ret) : "v"(p), "v"(v) : "memory");
    return ret;
}

// ---------------- init: f16 copies of initial hidden state ----------------
__global__ void k_init(const float* __restrict__ hin, half_t* __restrict__ h0h,
                       half_t* __restrict__ h1h) {
    int i = blockIdx.x * 256 + threadIdx.x;   // 512 blocks -> 131072 = NB*NH
    h0h[i] = (half_t)hin[i];
    h1h[i] = (half_t)hin[NB * NH + i];
}

// ---------------- persistent GRU kernel ----------------
__global__ __launch_bounds__(NTH)
void k_gru(GP p) {
    extern __shared__ char lds[];   // [0,96K) W swz | [96K..) h master | meta @104K
    const int tid = threadIdx.x;
    const int l   = tid & 63;
    const int wv  = tid >> 6;               // 0..7
    const int bid = blockIdx.x;
    const int role = (bid < 64) ? 0 : 1;
    const int lc   = bid - 64;              // L1 block index 0..127
    const int colbase = role ? lc * 8 : bid * 16;
    float* hl  = (float*)(lds + 98304);     // block-private h master f32
    int* meta  = (int*)(lds + 106496);
    unsigned* bar = p.bar;

    const int cloc = l & 15;
    const int col8 = cloc & 7;

    // ---- one-time: W slices f32 -> f16 into LDS (48 rows x 1024, XOR-swizzled)
    {
        for (int i = tid; i < 12288; i += NTH) {   // float4 chunks: 48 rows x 256
            int row = i >> 8, j = i & 255;
            const float* Wsrc;
            int wrow;
            if (role == 0) {               // rows: gate g (0..2) x 16 cols
                Wsrc = p.Whh0; wrow = (row >> 4) * NH + colbase + (row & 15);
            } else {                        // rows: plane (0..5) x 8 cols; plane<3 Wih1, else Whh1
                int plane = row >> 3, cl = row & 7;
                Wsrc = (plane < 3) ? p.Wih1 : p.Whh1;
                int g = (plane < 3) ? plane : plane - 3;
                wrow = g * NH + colbase + cl;
            }
            float4 v = *(const float4*)(Wsrc + (size_t)wrow * NH + j * 4);
            union { half_t h[4]; uint2 u; } cv;
            cv.h[0] = (half_t)v.x; cv.h[1] = (half_t)v.y;
            cv.h[2] = (half_t)v.z; cv.h[3] = (half_t)v.w;
            *(uint2*)(lds + (row * 2048 + ((j * 8) ^ ((row & 7) << 4)))) = cv.u;
        }
        // h master f32 into LDS
        if (role == 0) {
            for (int i = tid; i < NB * 16; i += NTH)
                hl[i] = p.hin[(size_t)(i >> 4) * NH + colbase + (i & 15)];
        } else {
            for (int i = tid; i < NB * 8; i += NTH)
                hl[i] = p.hin[(size_t)NB * NH + (size_t)(i >> 3) * NH + colbase + (i & 7)];
        }
    }

    // ---- one-time: XCD discovery + registration + flat init barrier (AG scope)
    if (tid == 0) {
        unsigned x;
        asm volatile("s_getreg_b32 %0, hwreg(HW_REG_XCC_ID)" : "=s"(x));
        x &= 7;
        unsigned r = aadd(bar + XCNT + x * 32, 1u);
        asm volatile("s_waitcnt vmcnt(0)" ::: "memory");
        aadd(bar + INITL, 1u);
        while (ald(bar + INITL) < NBLK) __builtin_amdgcn_s_sleep(1);
        int nn = 0, cnt = 0;
        for (int k = 0; k < 8; ++k) {
            unsigned c = ald(bar + XCNT + k * 32);
            if (c) ++cnt;
            if (k == (int)x) nn = (int)c;
        }
        meta[0] = (int)x; meta[1] = (int)r; meta[2] = nn; meta[3] = cnt;
    }
    __syncthreads();
    const int xcd_  = meta[0];
    const int rank_ = meta[1];
    const int n_    = meta[2];
    const int nx_   = meta[3];

    // ---- per-role constants
    float bi_[3] = {0,0,0}, bh_[3] = {0,0,0}, wx_[3] = {0,0,0}, fcwv = 0.f, fcb_ = 0.f;
    float bi_lo = 0.f, bh_lo = 0.f, bi2 = 0.f, bh2 = 0.f;
    if (role == 0) {
        int c = colbase + cloc;
        #pragma unroll
        for (int g = 0; g < 3; ++g) {
            bi_[g] = p.bih0[g * NH + c]; bh_[g] = p.bhh0[g * NH + c];
            wx_[g] = p.Wih0[g * NH + c];
        }
        fcb_ = p.fcb[0];
    } else {
        int glo = cloc >> 3;                   // 0: r-gate, 1: z-gate (mixed tile)
        int c8 = colbase + col8;
        bi_lo = p.bih1[glo * NH + c8]; bh_lo = p.bhh1[glo * NH + c8];
        bi2   = p.bih1[2 * NH + c8];   bh2   = p.bhh1[2 * NH + c8];
        fcwv  = p.fcw[c8];
    }

    // B-tile row bases (lds rows), shared rmask (all rows ≡ cloc&7 mod 8)
    const int rb_l0[3] = { cloc * 2048, (16 + cloc) * 2048, (32 + cloc) * 2048 };
    const int rb_l1[4] = { cloc * 2048, (16 + col8) * 2048, (24 + cloc) * 2048, (40 + col8) * 2048 };
    const int rmask = (col8) << 4;
    const int kb0 = (l >> 4) << 4;                 // byte offset of lane's k-chunk
    const int arow = wv * 16 + cloc;               // A row this lane loads
    const int b0base = wv * 16 + ((l >> 4) << 2);  // first output batch row
    const int aloff = (l >> 4) * 2048 + arow * 16; // lane offset in region [kq][row] layout

    // ---- global barrier (R5-proven)
    auto gbar = [&](unsigned t) {
        __syncthreads();   // compiler drains vmcnt before s_barrier -> stores MALL-visible
        if (tid == 0) {
            l2add(bar + XARR + xcd_ * 32, 1u);
            if (rank_ == 0) {
                while (l2add_rtn(bar + XARR + xcd_ * 32, 0u) < (unsigned)n_ * t)
                    __builtin_amdgcn_s_sleep(1);
                unsigned old = aadd(bar + GLOBL, 1u);
                if (old == (unsigned)nx_ * t - 1u) aadd(bar + RELL, 1u);
            }
            while (ald(bar + RELL) < t) __builtin_amdgcn_s_sleep(1);
        }
        __syncthreads();
        asm volatile("buffer_inv" ::: "memory");   // L1-only invalidate
    };

    // ---- per-phase: pull fresh h into this XCD's region (transposed [kq][row])
    auto xcopy = [&](const half_t* h0s, const half_t* h1s, int slot) {
        char* dst = p.reg + ((size_t)(xcd_ * 2 + slot)) * 524288;
        for (int idx = rank_ * NTH + tid; idx < 32768; idx += n_ * NTH) {
            int which = idx >> 14, kq = (idx >> 7) & 127, row = idx & 127;
            const half_t* s = (which ? h1s : h0s) + row * 1024 + kq * 8;
            union { u64 u[2]; uint4 v; } t;
            t.u[0] = ldu64(s);
            t.u[1] = ldu64(s + 4);
            *(uint4*)(dst + which * 262144 + (size_t)(kq * 128 + row) * 16) = t.v;
        }
    };
    auto csync = [&](unsigned ct) {   // XCD-local copy barrier: RMW arrive, RMW poll
        __syncthreads();
        if (tid == 0) {
            l2add(bar + XCPY + xcd_ * 32, 1u);
            while (l2add_rtn(bar + XCPY + xcd_ * 32, 0u) < (unsigned)n_ * ct)
                __builtin_amdgcn_s_sleep(1);
        }
        __syncthreads();
    };

    // ---- L0 GEMM: 3 gate tiles, A = h0 copy
    auto gemm_l0 = [&](const char* regA, f32x4 (&acc)[3]) {
        const char* ap = regA + aloff;
        #pragma unroll 8
        for (int ks = 0; ks < 32; ++ks) {
            f16x8 a = *(const f16x8*)(ap + (size_t)ks * 8192);
            int kb = ks * 64 + kb0;
            #pragma unroll
            for (int g = 0; g < 3; ++g) {
                f16x8 bf = *(const f16x8*)(lds + rb_l0[g] + (kb ^ rmask));
                acc[g] = __builtin_amdgcn_mfma_f32_16x16x32_f16(a, bf, acc[g], 0, 0, 0);
            }
        }
    };

    // ---- L1 GEMM: 4 mixed tiles; A0 = h0 copy (gi), A1 = h1 copy (gh)
    auto gemm_l1 = [&](const char* regA, f32x4 (&acc)[4]) {
        const char* ap0 = regA + aloff;
        const char* ap1 = regA + 262144 + aloff;
        #pragma unroll 8
        for (int ks = 0; ks < 32; ++ks) {
            f16x8 a0 = *(const f16x8*)(ap0 + (size_t)ks * 8192);
            f16x8 a1 = *(const f16x8*)(ap1 + (size_t)ks * 8192);
            int kb = ks * 64 + kb0;
            f16x8 b0 = *(const f16x8*)(lds + rb_l1[0] + (kb ^ rmask));
            acc[0] = __builtin_amdgcn_mfma_f32_16x16x32_f16(a0, b0, acc[0], 0, 0, 0);
            f16x8 b1 = *(const f16x8*)(lds + rb_l1[1] + (kb ^ rmask));
            acc[1] = __builtin_amdgcn_mfma_f32_16x16x32_f16(a0, b1, acc[1], 0, 0, 0);
            f16x8 b2 = *(const f16x8*)(lds + rb_l1[2] + (kb ^ rmask));
            acc[2] = __builtin_amdgcn_mfma_f32_16x16x32_f16(a1, b2, acc[2], 0, 0, 0);
            f16x8 b3 = *(const f16x8*)(lds + rb_l1[3] + (kb ^ rmask));
            acc[3] = __builtin_amdgcn_mfma_f32_16x16x32_f16(a1, b3, acc[3], 0, 0, 0);
        }
    };

    // pack 4 lanes' f16 values into one u64, store coherent (sc1); active lanes: mask16
    auto pack_store16 = [&](half_t* hw, int b, float hn) {   // L0: 16 cols
        unsigned v = (unsigned)__builtin_bit_cast(unsigned short, (half_t)hn);
        unsigned o = __shfl_xor(v, 1);
        unsigned pair = (l & 1) ? (o | (v << 16)) : (v | (o << 16));
        unsigned p2 = __shfl_xor(pair, 2);
        u64 quad = (l & 2) ? (((u64)pair << 32) | p2) : ((u64)pair | ((u64)p2 << 32));
        if ((l & 3) == 0) stu64(hw + (size_t)b * NH + ((colbase + cloc) & ~3), quad);
    };

    auto l0_epi = [&](const float xv[4], f32x4 (&acc)[3], half_t* hw) {
        #pragma unroll
        for (int q = 0; q < 4; ++q) {
            int b = b0base + q;
            float gh0 = acc[0][q] + bh_[0];
            float gh1 = acc[1][q] + bh_[1];
            float gh2 = acc[2][q] + bh_[2];
            float r_ = fast_sigmoid(xv[q] * wx_[0] + bi_[0] + gh0);
            float z_ = fast_sigmoid(xv[q] * wx_[1] + bi_[1] + gh1);
            float n_2 = fast_tanh(xv[q] * wx_[2] + bi_[2] + r_ * gh2);
            float hp = hl[b * 16 + cloc];
            float hn = (1.0f - z_) * n_2 + z_ * hp;
            hl[b * 16 + cloc] = hn;
            pack_store16(hw, b, hn);
        }
    };

    // L1 epilogue: mixed-lane gates; lanes cloc<8 own columns; optional fc partials
    auto l1_epi = [&](f32x4 (&acc)[4], half_t* hw, float* ydst) {
        #pragma unroll
        for (int q = 0; q < 4; ++q) {
            int b = b0base + q;
            // lane cloc<8: rz = r[col]; lane cloc>=8: rz = z[col-8]
            float rz = fast_sigmoid(acc[0][q] + bi_lo + acc[2][q] + bh_lo);
            float zv = __shfl_xor(rz, 8);            // lanes<8 receive z
            float n_2 = fast_tanh(acc[1][q] + bi2 + rz * (acc[3][q] + bh2));
            float hp = hl[b * 8 + col8];
            float hn = (1.0f - zv) * n_2 + zv * hp;
            if (cloc < 8) hl[b * 8 + col8] = hn;
            // pack-store 8 cols (lanes 0-7 of each 16-group hold cols 0-7)
            unsigned v = (unsigned)__builtin_bit_cast(unsigned short, (half_t)hn);
            unsigned o = __shfl_xor(v, 1);
            unsigned pair = (l & 1) ? (o | (v << 16)) : (v | (o << 16));
            unsigned p2 = __shfl_xor(pair, 2);
            u64 quad = (l & 2) ? (((u64)pair << 32) | p2) : ((u64)pair | ((u64)p2 << 32));
            if ((l & 3) == 0 && cloc < 8)
                stu64(hw + (size_t)b * NH + ((colbase + col8) & ~3), quad);
            if (ydst) {
                float s = hn * fcwv;                 // valid on lanes cloc<8
                s += __shfl_xor(s, 1);
                s += __shfl_xor(s, 2);
                s += __shfl_xor(s, 4);               // sum over 8 cols (lanes 0-7)
                if (cloc == 0) stf32(ydst + lc * NB + b, s);
            }
        }
    };

    // deterministic y reduce (role 0): 128 partials per batch, fixed tree order
    auto reduce_y = [&](float xv[4]) {
        #pragma unroll
        for (int q = 0; q < 4; ++q) {
            int b = b0base + q;
            float t0 = ldf32(p.ypart + (cloc * 8 + 0) * NB + b);
            float t1 = ldf32(p.ypart + (cloc * 8 + 1) * NB + b);
            float t2 = ldf32(p.ypart + (cloc * 8 + 2) * NB + b);
            float t3 = ldf32(p.ypart + (cloc * 8 + 3) * NB + b);
            float t4 = ldf32(p.ypart + (cloc * 8 + 4) * NB + b);
            float t5 = ldf32(p.ypart + (cloc * 8 + 5) * NB + b);
            float t6 = ldf32(p.ypart + (cloc * 8 + 6) * NB + b);
            float t7 = ldf32(p.ypart + (cloc * 8 + 7) * NB + b);
            xv[q] = ((t0 + t1) + (t2 + t3)) + ((t4 + t5) + (t6 + t7));
        }
        #pragma unroll
        for (int m = 1; m < 16; m <<= 1) {
            xv[0] += __shfl_xor(xv[0], m); xv[1] += __shfl_xor(xv[1], m);
            xv[2] += __shfl_xor(xv[2], m); xv[3] += __shfl_xor(xv[3], m);
        }
        #pragma unroll
        for (int q = 0; q < 4; ++q) xv[q] += fcb_;
    };

    unsigned tgt = 0, ctgt = 0;
    int cur0 = 0, cur1 = 0;
    f32x4 zero4 = {0.f, 0.f, 0.f, 0.f};
    float ysum[4] = {0.f, 0.f, 0.f, 0.f};   // role0: running sum of y0..y6

    auto COPY = [&]() {   // stage latest-written h buffers into region
        ++ctgt;
        int slot = (int)(ctgt & 1);
        xcopy(cur0 ? p.h0b1 : p.h0b0, cur1 ? p.h1b1 : p.h1b0, slot);
        csync(ctgt);
        return (const char*)(p.reg + (size_t)(xcd_ * 2 + slot) * 524288);
    };

    // ---- conditioning: phases 0 .. NS (2-stage pipeline); y0 partials at ph==NS
    for (int ph = 0; ph <= NS; ++ph) {
        float xv[4];
        if (role == 0 && ph < NS) {
            #pragma unroll
            for (int q = 0; q < 4; ++q) xv[q] = p.x[(size_t)(b0base + q) * NS + ph];
        }
        const char* regB = COPY();
        if (role == 0 && ph < NS) {
            f32x4 acc[3] = {zero4, zero4, zero4};
            gemm_l0(regB, acc);
            l0_epi(xv, acc, cur0 ? p.h0b0 : p.h0b1);
        } else if (role == 1 && ph >= 1) {
            f32x4 acc[4] = {zero4, zero4, zero4, zero4};
            gemm_l1(regB, acc);
            l1_epi(acc, cur1 ? p.h1b0 : p.h1b1, (ph == NS) ? p.ypart : nullptr);
        }
        ++tgt; gbar(tgt);
        if (ph < NS) cur0 ^= 1;
        if (ph >= 1) cur1 ^= 1;
    }

    // ---- forecast: 7 steps, 2 phases each (L0 with y -> L1 + fc partials)
    for (int i = 1; i < NF; ++i) {
        float xv[4];
        if (role == 0) {
            reduce_y(xv);
            #pragma unroll
            for (int q = 0; q < 4; ++q) ysum[q] += xv[q];
        }
        const char* regB = COPY();
        if (role == 0) {
            f32x4 acc[3] = {zero4, zero4, zero4};
            gemm_l0(regB, acc);
            l0_epi(xv, acc, cur0 ? p.h0b0 : p.h0b1);
        }
        ++tgt; gbar(tgt); cur0 ^= 1;

        regB = COPY();
        if (role == 1) {
            f32x4 acc[4] = {zero4, zero4, zero4, zero4};
            gemm_l1(regB, acc);
            l1_epi(acc, cur1 ? p.h1b0 : p.h1b1, p.ypart);
        }
        ++tgt; gbar(tgt); cur1 ^= 1;
    }

    // ---- final output: deterministic mean of forecasts + h_final export from LDS
    if (role == 0) {
        float y7[4];
        reduce_y(y7);   // y7 partials written in the last L1 phase, gbar'd
        if (bid == 0 && cloc == 0) {
            #pragma unroll
            for (int q = 0; q < 4; ++q)
                p.out[b0base + q] = (ysum[q] + y7[q]) * 0.125f;
        }
        float* ob = p.out + NB;
        for (int i = tid; i < NB * 16; i += NTH)
            ob[(size_t)(i >> 4) * NH + colbase + (i & 15)] = hl[i];
    } else {
        float* ob = p.out + NB + (size_t)NB * NH;
        for (int i = tid; i < NB * 8; i += NTH)
            ob[(size_t)(i >> 3) * NH + colbase + (i & 7)] = hl[i];
    }
}

extern "C" void kernel_launch(void* const* d_in, const int* in_sizes, int n_in,
                              void* d_out, int out_size, void* d_ws, size_t ws_size,
                              hipStream_t stream)
{
    GP p;
    p.x    = (const float*)d_in[0];
    p.hin  = (const float*)d_in[1];
    p.Wih0 = (const float*)d_in[2];
    p.Whh0 = (const float*)d_in[3];
    p.bih0 = (const float*)d_in[4];
    p.bhh0 = (const float*)d_in[5];
    p.Wih1 = (const float*)d_in[6];
    p.Whh1 = (const float*)d_in[7];
    p.bih1 = (const float*)d_in[8];
    p.bhh1 = (const float*)d_in[9];
    p.fcw  = (const float*)d_in[10];
    p.fcb  = (const float*)d_in[11];
    p.out  = (float*)d_out;

    char* ws = (char*)d_ws;
    p.bar   = (unsigned*)ws;                     ws += 8192;
    p.h0b0  = (half_t*)ws;                       ws += 262144;
    p.h0b1  = (half_t*)ws;                       ws += 262144;
    p.h1b0  = (half_t*)ws;                       ws += 262144;
    p.h1b1  = (half_t*)ws;                       ws += 262144;
    p.ypart = (float*)ws;                        ws += 65536;   // 128 blocks x 128 batches f32
    ws = (char*)(((size_t)ws + 4095) & ~(size_t)4095);
    p.reg   = ws;                                ws += 8 * 2 * 524288;   // 8 MiB

    hipMemsetAsync(p.bar, 0, 8192, stream);
    k_init<<<512, 256, 0, stream>>>(p.hin, p.h0b0, p.h1b0);

    void* args[] = { &p };
    if (hipLaunchCooperativeKernel((void*)k_gru, dim3(NBLK), dim3(NTH), args,
                                   106752, stream) != hipSuccess) {
        (void)hipGetLastError();
        // fallback: 192 blocks @ ~104KiB LDS = 1 block/CU on 256 CUs -> co-resident
        k_gru<<<dim3(NBLK), dim3(NTH), 106752, stream>>>(p);
    }
}

// Round 11
// 3500.568 us; speedup vs baseline: 1.0982x; 1.0982x over previous
//
#include <hip/hip_runtime.h>

#define NB 128      // batch
#define NH 1024     // hidden
#define NS 256      // conditioning sequence length
#define NF 8        // forecast length
#define NBLK 192    // persistent blocks: 64 L0 (16 cols) | 128 L1 (8 cols, gi+gh fused)
#define NTH 512     // 8 waves = 4 M-groups x 2 K-halves
#define AG  __HIP_MEMORY_SCOPE_AGENT

// barrier line indices (uint32 units; distinct >=128B-separated lines)
#define GLOBL 0            // MALL line: ONLY 8 rank0s add; nobody polls (last-detect)
#define RELL  64           // MALL line: 1 adder, 192 atomic-load pollers (R5-proven)
#define INITL 128
#define XCNT  192          // +32*xcd  (init registration)
#define XARR  512          // +32*xcd  (XCD-local L2: arrival, atomic RMW poll)
#define XCPY  1024         // +32*xcd  (XCD-local L2: copy barrier, atomic RMW poll)

typedef _Float16 half_t;
typedef _Float16 f16x8 __attribute__((ext_vector_type(8)));
typedef float f32x4 __attribute__((ext_vector_type(4)));
typedef unsigned long long u64;

struct GP {
    const float *x, *hin, *Wih0, *Whh0, *bih0, *bhh0, *Wih1, *Whh1, *bih1, *bhh1, *fcw, *fcb;
    float *ypart, *out;
    half_t *h0b0, *h0b1, *h1b0, *h1b1;
    char *reg;            // XCD-private A regions: [8 xcd][2 slot][h0 256K | h1 256K]
    unsigned *bar;
};

__device__ __forceinline__ float fast_sigmoid(float x) { return 1.0f / (1.0f + __expf(-x)); }
__device__ __forceinline__ float fast_tanh(float x) {
    float e = __expf(2.0f * x);
    return (e - 1.0f) / (e + 1.0f);
}

// ---- agent-scope (sc1 / MALL) accesses ----
__device__ __forceinline__ u64 ldu64(const void* p) {
    return __hip_atomic_load((const u64*)p, __ATOMIC_RELAXED, AG);
}
__device__ __forceinline__ void stu64(void* p, u64 v) {
    __hip_atomic_store((u64*)p, v, __ATOMIC_RELAXED, AG);
}
__device__ __forceinline__ float ldf32(const float* p) {
    return __hip_atomic_load(p, __ATOMIC_RELAXED, AG);
}
__device__ __forceinline__ void stf32(float* p, float v) {
    __hip_atomic_store(p, v, __ATOMIC_RELAXED, AG);
}
__device__ __forceinline__ unsigned aadd(unsigned* p, unsigned v) {
    return __hip_atomic_fetch_add(p, v, __ATOMIC_RELAXED, AG);
}
__device__ __forceinline__ unsigned ald(const unsigned* p) {   // sc1 atomic load (MALL-fresh)
    return __hip_atomic_load(p, __ATOMIC_RELAXED, AG);
}

// ---- XCD-local atomics (no sc1 -> execute in the local XCD's L2; always fresh) ----
__device__ __forceinline__ void l2add(unsigned* p, unsigned v) {
    asm volatile("global_atomic_add %0, %1, off" :: "v"(p), "v"(v) : "memory");
}
__device__ __forceinline__ unsigned l2add_rtn(unsigned* p, unsigned v) {
    unsigned ret;
    asm volatile("global_atomic_add %0, %1, %2, off sc0\n\ts_waitcnt vmcnt(0)"
                 : "=v"(ret) : "v"(p), "v"(v) : "memory");
    return ret;
}

// ---------------- init: f16 copies of initial hidden state ----------------
__global__ void k_init(const float* __restrict__ hin, half_t* __restrict__ h0h,
                       half_t* __restrict__ h1h) {
    int i = blockIdx.x * 256 + threadIdx.x;   // 512 blocks -> 131072 = NB*NH
    h0h[i] = (half_t)hin[i];
    h1h[i] = (half_t)hin[NB * NH + i];
}

// ---------------- persistent GRU kernel ----------------
__global__ __launch_bounds__(NTH)
void k_gru(GP p) {
    extern __shared__ char lds[];   // [0,96K) W swz | 8K h master | meta | 32K k-red scratch
    const int tid = threadIdx.x;
    const int l   = tid & 63;
    const int wv  = tid >> 6;               // 0..7
    const int mh  = wv & 3;                 // M-group: batches mh*32 .. mh*32+31
    const int kh  = wv >> 2;                // k-half: 0 (low 512) / 1 (high 512)
    const int bid = blockIdx.x;
    const int role = (bid < 64) ? 0 : 1;
    const int lc   = bid - 64;              // L1 block index 0..127
    const int colbase = role ? lc * 8 : bid * 16;
    float* hl  = (float*)(lds + 98304);     // block-private h master f32
    int* meta  = (int*)(lds + 106496);
    float* red = (float*)(lds + 106752);    // k-reduction scratch: 4 M-groups x 8KB
    unsigned* bar = p.bar;

    const int cloc = l & 15;
    const int col8 = cloc & 7;

    // ---- one-time: W slices f32 -> f16 into LDS (48 rows x 1024, XOR-swizzled)
    {
        for (int i = tid; i < 12288; i += NTH) {   // float4 chunks: 48 rows x 256
            int row = i >> 8, j = i & 255;
            const float* Wsrc;
            int wrow;
            if (role == 0) {               // rows: gate g (0..2) x 16 cols
                Wsrc = p.Whh0; wrow = (row >> 4) * NH + colbase + (row & 15);
            } else {                        // rows: plane (0..5) x 8 cols; plane<3 Wih1, else Whh1
                int plane = row >> 3, cl = row & 7;
                Wsrc = (plane < 3) ? p.Wih1 : p.Whh1;
                int g = (plane < 3) ? plane : plane - 3;
                wrow = g * NH + colbase + cl;
            }
            float4 v = *(const float4*)(Wsrc + (size_t)wrow * NH + j * 4);
            union { half_t h[4]; uint2 u; } cv;
            cv.h[0] = (half_t)v.x; cv.h[1] = (half_t)v.y;
            cv.h[2] = (half_t)v.z; cv.h[3] = (half_t)v.w;
            *(uint2*)(lds + (row * 2048 + ((j * 8) ^ ((row & 7) << 4)))) = cv.u;
        }
        // h master f32 into LDS
        if (role == 0) {
            for (int i = tid; i < NB * 16; i += NTH)
                hl[i] = p.hin[(size_t)(i >> 4) * NH + colbase + (i & 15)];
        } else {
            for (int i = tid; i < NB * 8; i += NTH)
                hl[i] = p.hin[(size_t)NB * NH + (size_t)(i >> 3) * NH + colbase + (i & 7)];
        }
    }

    // ---- one-time: XCD discovery + registration + flat init barrier (AG scope)
    if (tid == 0) {
        unsigned x;
        asm volatile("s_getreg_b32 %0, hwreg(HW_REG_XCC_ID)" : "=s"(x));
        x &= 7;
        unsigned r = aadd(bar + XCNT + x * 32, 1u);
        asm volatile("s_waitcnt vmcnt(0)" ::: "memory");
        aadd(bar + INITL, 1u);
        while (ald(bar + INITL) < NBLK) __builtin_amdgcn_s_sleep(1);
        int nn = 0, cnt = 0;
        for (int k = 0; k < 8; ++k) {
            unsigned c = ald(bar + XCNT + k * 32);
            if (c) ++cnt;
            if (k == (int)x) nn = (int)c;
        }
        meta[0] = (int)x; meta[1] = (int)r; meta[2] = nn; meta[3] = cnt;
    }
    __syncthreads();
    const int xcd_  = meta[0];
    const int rank_ = meta[1];
    const int n_    = meta[2];
    const int nx_   = meta[3];

    // ---- per-role constants
    float bi_[3] = {0,0,0}, bh_[3] = {0,0,0}, wx_[3] = {0,0,0}, fcwv = 0.f, fcb_ = 0.f;
    float bi_lo = 0.f, bh_lo = 0.f, bi2 = 0.f, bh2 = 0.f;
    if (role == 0) {
        int c = colbase + cloc;
        #pragma unroll
        for (int g = 0; g < 3; ++g) {
            bi_[g] = p.bih0[g * NH + c]; bh_[g] = p.bhh0[g * NH + c];
            wx_[g] = p.Wih0[g * NH + c];
        }
        fcb_ = p.fcb[0];
    } else {
        int glo = cloc >> 3;                   // 0: r-gate, 1: z-gate (mixed tile)
        int c8 = colbase + col8;
        bi_lo = p.bih1[glo * NH + c8]; bh_lo = p.bhh1[glo * NH + c8];
        bi2   = p.bih1[2 * NH + c8];   bh2   = p.bhh1[2 * NH + c8];
        fcwv  = p.fcw[c8];
    }

    // B-tile row bases (lds rows), shared rmask (all rows ≡ col8 mod 8)
    const int rb_l0[3] = { cloc * 2048, (16 + cloc) * 2048, (32 + cloc) * 2048 };
    const int rb_l1[4] = { cloc * 2048, (16 + col8) * 2048, (24 + cloc) * 2048, (40 + col8) * 2048 };
    const int rmask = col8 << 4;
    const int kb_base = kh * 1024 + ((l >> 4) << 4);   // B byte offset within 2048B row
    const int b0base = mh * 32 + ((l >> 4) << 2);      // first batch row of M-subtile 0
    // A lane offset in region [kq][row] layout: kq = kh*64 + (l>>4) + ks*4
    const int aloff = (kh * 64 + (l >> 4)) * 2048 + (mh * 32 + cloc) * 16;

    // ---- global barrier (R5-proven)
    auto gbar = [&](unsigned t) {
        __syncthreads();   // compiler drains vmcnt before s_barrier -> stores MALL-visible
        if (tid == 0) {
            l2add(bar + XARR + xcd_ * 32, 1u);
            if (rank_ == 0) {
                while (l2add_rtn(bar + XARR + xcd_ * 32, 0u) < (unsigned)n_ * t)
                    __builtin_amdgcn_s_sleep(1);
                unsigned old = aadd(bar + GLOBL, 1u);
                if (old == (unsigned)nx_ * t - 1u) aadd(bar + RELL, 1u);
            }
            while (ald(bar + RELL) < t) __builtin_amdgcn_s_sleep(1);
        }
        __syncthreads();
        asm volatile("buffer_inv" ::: "memory");   // L1-only invalidate
    };

    // ---- per-phase: pull fresh h into this XCD's region (transposed [kq][row])
    auto xcopy = [&](const half_t* h0s, const half_t* h1s, int slot) {
        char* dst = p.reg + ((size_t)(xcd_ * 2 + slot)) * 524288;
        for (int idx = rank_ * NTH + tid; idx < 32768; idx += n_ * NTH) {
            int which = idx >> 14, kq = (idx >> 7) & 127, row = idx & 127;
            const half_t* s = (which ? h1s : h0s) + row * 1024 + kq * 8;
            union { u64 u[2]; uint4 v; } t;
            t.u[0] = ldu64(s);
            t.u[1] = ldu64(s + 4);
            *(uint4*)(dst + which * 262144 + (size_t)(kq * 128 + row) * 16) = t.v;
        }
    };
    auto csync = [&](unsigned ct) {   // XCD-local copy barrier: RMW arrive, RMW poll
        __syncthreads();
        if (tid == 0) {
            l2add(bar + XCPY + xcd_ * 32, 1u);
            while (l2add_rtn(bar + XCPY + xcd_ * 32, 0u) < (unsigned)n_ * ct)
                __builtin_amdgcn_s_sleep(1);
        }
        __syncthreads();
    };

    // ---- L0 GEMM: 3 gate tiles x 2 M-subtiles, k-half per wave
    auto gemm_l0 = [&](const char* regA, f32x4 (&acc)[2][3]) {
        const char* ap = regA + aloff;
        #pragma unroll 8
        for (int ks = 0; ks < 16; ++ks) {
            f16x8 a0 = *(const f16x8*)(ap + ks * 8192);
            f16x8 a1 = *(const f16x8*)(ap + ks * 8192 + 256);
            int kb = kb_base + ks * 64;
            #pragma unroll
            for (int g = 0; g < 3; ++g) {
                f16x8 bf = *(const f16x8*)(lds + rb_l0[g] + (kb ^ rmask));
                acc[0][g] = __builtin_amdgcn_mfma_f32_16x16x32_f16(a0, bf, acc[0][g], 0, 0, 0);
                acc[1][g] = __builtin_amdgcn_mfma_f32_16x16x32_f16(a1, bf, acc[1][g], 0, 0, 0);
            }
        }
    };

    // ---- L1 GEMM: 4 mixed tiles x 2 M-subtiles; A0 = h0 (gi), A1 = h1 (gh)
    auto gemm_l1 = [&](const char* regA, f32x4 (&acc)[2][4]) {
        const char* ap0 = regA + aloff;
        const char* ap1 = regA + 262144 + aloff;
        #pragma unroll 4
        for (int ks = 0; ks < 16; ++ks) {
            f16x8 a00 = *(const f16x8*)(ap0 + ks * 8192);
            f16x8 a01 = *(const f16x8*)(ap0 + ks * 8192 + 256);
            f16x8 a10 = *(const f16x8*)(ap1 + ks * 8192);
            f16x8 a11 = *(const f16x8*)(ap1 + ks * 8192 + 256);
            int kb = kb_base + ks * 64;
            f16x8 b0 = *(const f16x8*)(lds + rb_l1[0] + (kb ^ rmask));
            acc[0][0] = __builtin_amdgcn_mfma_f32_16x16x32_f16(a00, b0, acc[0][0], 0, 0, 0);
            acc[1][0] = __builtin_amdgcn_mfma_f32_16x16x32_f16(a01, b0, acc[1][0], 0, 0, 0);
            f16x8 b1 = *(const f16x8*)(lds + rb_l1[1] + (kb ^ rmask));
            acc[0][1] = __builtin_amdgcn_mfma_f32_16x16x32_f16(a00, b1, acc[0][1], 0, 0, 0);
            acc[1][1] = __builtin_amdgcn_mfma_f32_16x16x32_f16(a01, b1, acc[1][1], 0, 0, 0);
            f16x8 b2 = *(const f16x8*)(lds + rb_l1[2] + (kb ^ rmask));
            acc[0][2] = __builtin_amdgcn_mfma_f32_16x16x32_f16(a10, b2, acc[0][2], 0, 0, 0);
            acc[1][2] = __builtin_amdgcn_mfma_f32_16x16x32_f16(a11, b2, acc[1][2], 0, 0, 0);
            f16x8 b3 = *(const f16x8*)(lds + rb_l1[3] + (kb ^ rmask));
            acc[0][3] = __builtin_amdgcn_mfma_f32_16x16x32_f16(a10, b3, acc[0][3], 0, 0, 0);
            acc[1][3] = __builtin_amdgcn_mfma_f32_16x16x32_f16(a11, b3, acc[1][3], 0, 0, 0);
        }
    };

    // pack 4 lanes' f16 values into one u64, store coherent (sc1)
    auto pack_store16 = [&](half_t* hw, int b, float hn) {   // L0: 16 cols
        unsigned v = (unsigned)__builtin_bit_cast(unsigned short, (half_t)hn);
        unsigned o = __shfl_xor(v, 1);
        unsigned pair = (l & 1) ? (o | (v << 16)) : (v | (o << 16));
        unsigned p2 = __shfl_xor(pair, 2);
        u64 quad = (l & 2) ? (((u64)pair << 32) | p2) : ((u64)pair | ((u64)p2 << 32));
        if ((l & 3) == 0) stu64(hw + (size_t)b * NH + ((colbase + cloc) & ~3), quad);
    };

    auto l0_epi = [&](const float xv[2][4], f32x4 (&acc)[2][3], half_t* hw) {
        #pragma unroll
        for (int m = 0; m < 2; ++m) {
            #pragma unroll
            for (int q = 0; q < 4; ++q) {
                int b = b0base + m * 16 + q;
                float gh0 = acc[m][0][q] + bh_[0];
                float gh1 = acc[m][1][q] + bh_[1];
                float gh2 = acc[m][2][q] + bh_[2];
                float r_ = fast_sigmoid(xv[m][q] * wx_[0] + bi_[0] + gh0);
                float z_ = fast_sigmoid(xv[m][q] * wx_[1] + bi_[1] + gh1);
                float n_2 = fast_tanh(xv[m][q] * wx_[2] + bi_[2] + r_ * gh2);
                float hp = hl[b * 16 + cloc];
                float hn = (1.0f - z_) * n_2 + z_ * hp;
                hl[b * 16 + cloc] = hn;
                pack_store16(hw, b, hn);
            }
        }
    };

    // L1 epilogue: mixed-lane gates; lanes cloc<8 own columns; optional fc partials
    auto l1_epi = [&](f32x4 (&acc)[2][4], half_t* hw, float* ydst) {
        #pragma unroll
        for (int m = 0; m < 2; ++m) {
            #pragma unroll
            for (int q = 0; q < 4; ++q) {
                int b = b0base + m * 16 + q;
                float rz = fast_sigmoid(acc[m][0][q] + bi_lo + acc[m][2][q] + bh_lo);
                float zv = __shfl_xor(rz, 8);            // lanes<8 receive z
                float n_2 = fast_tanh(acc[m][1][q] + bi2 + rz * (acc[m][3][q] + bh2));
                float hp = hl[b * 8 + col8];
                float hn = (1.0f - zv) * n_2 + zv * hp;
                if (cloc < 8) hl[b * 8 + col8] = hn;
                unsigned v = (unsigned)__builtin_bit_cast(unsigned short, (half_t)hn);
                unsigned o = __shfl_xor(v, 1);
                unsigned pair = (l & 1) ? (o | (v << 16)) : (v | (o << 16));
                unsigned p2 = __shfl_xor(pair, 2);
                u64 quad = (l & 2) ? (((u64)pair << 32) | p2) : ((u64)pair | ((u64)p2 << 32));
                if ((l & 3) == 0 && cloc < 8)
                    stu64(hw + (size_t)b * NH + ((colbase + col8) & ~3), quad);
                if (ydst) {
                    float s = hn * fcwv;                 // valid on lanes cloc<8
                    s += __shfl_xor(s, 1);
                    s += __shfl_xor(s, 2);
                    s += __shfl_xor(s, 4);               // sum over 8 cols (lanes 0-7)
                    if (cloc == 0) stf32(ydst + lc * NB + b, s);
                }
            }
        }
    };

    // deterministic y reduce (role 0, kh==0 waves): 128 partials/batch, fixed tree
    auto reduce_y = [&](float xv[2][4]) {
        #pragma unroll
        for (int m = 0; m < 2; ++m) {
            #pragma unroll
            for (int q = 0; q < 4; ++q) {
                int b = b0base + m * 16 + q;
                float t[8];
                #pragma unroll
                for (int j = 0; j < 8; ++j)
                    t[j] = ldf32(p.ypart + (cloc * 8 + j) * NB + b);
                float s = ((t[0] + t[1]) + (t[2] + t[3])) + ((t[4] + t[5]) + (t[6] + t[7]));
                #pragma unroll
                for (int mm = 1; mm < 16; mm <<= 1) s += __shfl_xor(s, mm);
                xv[m][q] = s + fcb_;
            }
        }
    };

    unsigned tgt = 0, ctgt = 0;
    int cur0 = 0, cur1 = 0;
    f32x4 zero4 = {0.f, 0.f, 0.f, 0.f};
    float ysum[2][4] = {{0.f,0.f,0.f,0.f},{0.f,0.f,0.f,0.f}};

    auto COPY = [&]() {   // stage latest-written h buffers into region
        ++ctgt;
        int slot = (int)(ctgt & 1);
        xcopy(cur0 ? p.h0b1 : p.h0b0, cur1 ? p.h1b1 : p.h1b0, slot);
        csync(ctgt);
        return (const char*)(p.reg + (size_t)(xcd_ * 2 + slot) * 524288);
    };

    float* redbase = red + mh * 2048 + (l << 2);   // per-lane scratch base (floats)

    // ---- conditioning: phases 0 .. NS (2-stage pipeline); y0 partials at ph==NS
    for (int ph = 0; ph <= NS; ++ph) {
        float xv[2][4];
        if (role == 0 && ph < NS && kh == 0) {
            #pragma unroll
            for (int m = 0; m < 2; ++m)
                #pragma unroll
                for (int q = 0; q < 4; ++q)
                    xv[m][q] = p.x[(size_t)(b0base + m * 16 + q) * NS + ph];
        }
        const char* regB = COPY();
        if (role == 0 && ph < NS) {
            f32x4 acc[2][3];
            #pragma unroll
            for (int m = 0; m < 2; ++m) { acc[m][0] = zero4; acc[m][1] = zero4; acc[m][2] = zero4; }
            gemm_l0(regB, acc);
            if (kh == 1) {
                #pragma unroll
                for (int m = 0; m < 2; ++m)
                    #pragma unroll
                    for (int g = 0; g < 3; ++g)
                        *(f32x4*)(redbase + (m * 3 + g) * 256) = acc[m][g];
            }
            __syncthreads();
            if (kh == 0) {
                #pragma unroll
                for (int m = 0; m < 2; ++m)
                    #pragma unroll
                    for (int g = 0; g < 3; ++g)
                        acc[m][g] += *(const f32x4*)(redbase + (m * 3 + g) * 256);
                l0_epi(xv, acc, cur0 ? p.h0b0 : p.h0b1);
            }
        } else if (role == 1 && ph >= 1) {
            f32x4 acc[2][4];
            #pragma unroll
            for (int m = 0; m < 2; ++m)
                #pragma unroll
                for (int g = 0; g < 4; ++g) acc[m][g] = zero4;
            gemm_l1(regB, acc);
            if (kh == 1) {
                #pragma unroll
                for (int m = 0; m < 2; ++m)
                    #pragma unroll
                    for (int g = 0; g < 4; ++g)
                        *(f32x4*)(redbase + (m * 4 + g) * 256) = acc[m][g];
            }
            __syncthreads();
            if (kh == 0) {
                #pragma unroll
                for (int m = 0; m < 2; ++m)
                    #pragma unroll
                    for (int g = 0; g < 4; ++g)
                        acc[m][g] += *(const f32x4*)(redbase + (m * 4 + g) * 256);
                l1_epi(acc, cur1 ? p.h1b0 : p.h1b1, (ph == NS) ? p.ypart : nullptr);
            }
        }
        ++tgt; gbar(tgt);
        if (ph < NS) cur0 ^= 1;
        if (ph >= 1) cur1 ^= 1;
    }

    // ---- forecast: 7 steps, 2 phases each (L0 with y -> L1 + fc partials)
    for (int i = 1; i < NF; ++i) {
        float xv[2][4];
        if (role == 0 && kh == 0) {
            reduce_y(xv);
            #pragma unroll
            for (int m = 0; m < 2; ++m)
                #pragma unroll
                for (int q = 0; q < 4; ++q) ysum[m][q] += xv[m][q];
        }
        const char* regB = COPY();
        if (role == 0) {
            f32x4 acc[2][3];
            #pragma unroll
            for (int m = 0; m < 2; ++m) { acc[m][0] = zero4; acc[m][1] = zero4; acc[m][2] = zero4; }
            gemm_l0(regB, acc);
            if (kh == 1) {
                #pragma unroll
                for (int m = 0; m < 2; ++m)
                    #pragma unroll
                    for (int g = 0; g < 3; ++g)
                        *(f32x4*)(redbase + (m * 3 + g) * 256) = acc[m][g];
            }
            __syncthreads();
            if (kh == 0) {
                #pragma unroll
                for (int m = 0; m < 2; ++m)
                    #pragma unroll
                    for (int g = 0; g < 3; ++g)
                        acc[m][g] += *(const f32x4*)(redbase + (m * 3 + g) * 256);
                l0_epi(xv, acc, cur0 ? p.h0b0 : p.h0b1);
            }
        }
        ++tgt; gbar(tgt); cur0 ^= 1;

        regB = COPY();
        if (role == 1) {
            f32x4 acc[2][4];
            #pragma unroll
            for (int m = 0; m < 2; ++m)
                #pragma unroll
                for (int g = 0; g < 4; ++g) acc[m][g] = zero4;
            gemm_l1(regB, acc);
            if (kh == 1) {
                #pragma unroll
                for (int m = 0; m < 2; ++m)
                    #pragma unroll
                    for (int g = 0; g < 4; ++g)
                        *(f32x4*)(redbase + (m * 4 + g) * 256) = acc[m][g];
            }
            __syncthreads();
            if (kh == 0) {
                #pragma unroll
                for (int m = 0; m < 2; ++m)
                    #pragma unroll
                    for (int g = 0; g < 4; ++g)
                        acc[m][g] += *(const f32x4*)(redbase + (m * 4 + g) * 256);
                l1_epi(acc, cur1 ? p.h1b0 : p.h1b1, p.ypart);
            }
        }
        ++tgt; gbar(tgt); cur1 ^= 1;
    }

    // ---- final output: deterministic mean of forecasts + h_final export from LDS
    if (role == 0 && kh == 0) {
        float y7[2][4];
        reduce_y(y7);   // y7 partials written in the last L1 phase, gbar'd
        if (bid == 0 && cloc == 0) {
            #pragma unroll
            for (int m = 0; m < 2; ++m)
                #pragma unroll
                for (int q = 0; q < 4; ++q)
                    p.out[b0base + m * 16 + q] = (ysum[m][q] + y7[m][q]) * 0.125f;
        }
    }
    if (role == 0) {
        float* ob = p.out + NB;
        for (int i = tid; i < NB * 16; i += NTH)
            ob[(size_t)(i >> 4) * NH + colbase + (i & 15)] = hl[i];
    } else {
        float* ob = p.out + NB + (size_t)NB * NH;
        for (int i = tid; i < NB * 8; i += NTH)
            ob[(size_t)(i >> 3) * NH + colbase + (i & 7)] = hl[i];
    }
}

extern "C" void kernel_launch(void* const* d_in, const int* in_sizes, int n_in,
                              void* d_out, int out_size, void* d_ws, size_t ws_size,
                              hipStream_t stream)
{
    GP p;
    p.x    = (const float*)d_in[0];
    p.hin  = (const float*)d_in[1];
    p.Wih0 = (const float*)d_in[2];
    p.Whh0 = (const float*)d_in[3];
    p.bih0 = (const float*)d_in[4];
    p.bhh0 = (const float*)d_in[5];
    p.Wih1 = (const float*)d_in[6];
    p.Whh1 = (const float*)d_in[7];
    p.bih1 = (const float*)d_in[8];
    p.bhh1 = (const float*)d_in[9];
    p.fcw  = (const float*)d_in[10];
    p.fcb  = (const float*)d_in[11];
    p.out  = (float*)d_out;

    char* ws = (char*)d_ws;
    p.bar   = (unsigned*)ws;                     ws += 8192;
    p.h0b0  = (half_t*)ws;                       ws += 262144;
    p.h0b1  = (half_t*)ws;                       ws += 262144;
    p.h1b0  = (half_t*)ws;                       ws += 262144;
    p.h1b1  = (half_t*)ws;                       ws += 262144;
    p.ypart = (float*)ws;                        ws += 65536;   // 128 blocks x 128 batches f32
    ws = (char*)(((size_t)ws + 4095) & ~(size_t)4095);
    p.reg   = ws;                                ws += 8 * 2 * 524288;   // 8 MiB

    hipMemsetAsync(p.bar, 0, 8192, stream);
    k_init<<<512, 256, 0, stream>>>(p.hin, p.h0b0, p.h1b0);

    void* args[] = { &p };
    if (hipLaunchCooperativeKernel((void*)k_gru, dim3(NBLK), dim3(NTH), args,
                                   139520, stream) != hipSuccess) {
        (void)hipGetLastError();
        // fallback: 192 blocks @ ~136KiB LDS = 1 block/CU on 256 CUs -> co-resident
        k_gru<<<dim3(NBLK), dim3(NTH), 139520, stream>>>(p);
    }
}